// Round 1
// baseline (4098.540 us; speedup 1.0000x reference)
//
#include <hip/hip_runtime.h>

#define T_STEPS 512
#define BATCH   64
#define IN      512
#define HID     1024
#define GDIM    4096
#define MROWS   (T_STEPS * BATCH)

typedef __attribute__((ext_vector_type(8))) short bf16x8_t;
typedef __attribute__((ext_vector_type(4))) float f32x4_t;

__device__ __forceinline__ unsigned short f2bf(float f) {
  union { float f; unsigned int u; } v; v.f = f;
  unsigned int r = v.u + 0x7FFFu + ((v.u >> 16) & 1u);
  return (unsigned short)(r >> 16);
}
__device__ __forceinline__ float bf2f(unsigned short u) {
  union { unsigned int u; float f; } v; v.u = ((unsigned int)u) << 16;
  return v.f;
}
__device__ __forceinline__ float sigmoidf_(float x) {
  return 1.0f / (1.0f + __expf(-x));
}

// ---------------- fp32 -> bf16 conversion ----------------
__global__ void k_cvt(const float* __restrict__ src, unsigned short* __restrict__ dst, int n) {
  int i = (blockIdx.x * blockDim.x + threadIdx.x) * 4;
  if (i + 3 < n) {
    float4 f = *(const float4*)(src + i);
    ushort4 o;
    o.x = f2bf(f.x); o.y = f2bf(f.y); o.z = f2bf(f.z); o.w = f2bf(f.w);
    *(ushort4*)(dst + i) = o;
  }
}

__global__ void k_bias(const float* __restrict__ a, const float* __restrict__ b,
                       float* __restrict__ o) {
  int i = blockIdx.x * blockDim.x + threadIdx.x;
  if (i < GDIM) o[i] = a[i] + b[i];
}

// ---------------- x_proj GEMM: [32768 x 512] @ [512 x 4096]^T(W_ih) ----------------
// 128x128 tile, 4 waves (2x2), each wave 64x64 (4x4 fragments of 16x16x32 bf16 MFMA).
__global__ __launch_bounds__(256) void k_xproj(
    const float* __restrict__ x,
    const unsigned short* __restrict__ Wih,
    const float* __restrict__ bias,
    unsigned short* __restrict__ xproj)
{
  const int AP = 40;  // padded row stride (shorts): 80B -> 2-way banks (free)
  __shared__ unsigned short Alds[128 * AP];
  __shared__ unsigned short Blds[128 * AP];
  const int tid = threadIdx.x;
  const int w = tid >> 6, l = tid & 63;
  const int m0 = blockIdx.y * 128, n0 = blockIdx.x * 128;
  const int wm = (w >> 1) * 64, wn = (w & 1) * 64;
  f32x4_t acc[4][4] = {};

  for (int k0 = 0; k0 < IN; k0 += 32) {
    // stage A: x fp32 -> bf16, 128 rows x 32 k
    #pragma unroll
    for (int it = 0; it < 2; ++it) {
      int chunk = tid + it * 256;           // 0..511
      int row = chunk >> 2;
      int kc  = (chunk & 3) * 8;
      const float* src = x + (size_t)(m0 + row) * IN + k0 + kc;
      float4 f0 = *(const float4*)(src);
      float4 f1 = *(const float4*)(src + 4);
      union { bf16x8_t v; unsigned short s[8]; } u;
      u.s[0]=f2bf(f0.x); u.s[1]=f2bf(f0.y); u.s[2]=f2bf(f0.z); u.s[3]=f2bf(f0.w);
      u.s[4]=f2bf(f1.x); u.s[5]=f2bf(f1.y); u.s[6]=f2bf(f1.z); u.s[7]=f2bf(f1.w);
      *(bf16x8_t*)&Alds[row * AP + kc] = u.v;
    }
    // stage B: W_ih bf16 rows (g), 128 x 32
    #pragma unroll
    for (int it = 0; it < 2; ++it) {
      int chunk = tid + it * 256;
      int row = chunk >> 2;
      int kc  = (chunk & 3) * 8;
      *(bf16x8_t*)&Blds[row * AP + kc] =
          *(const bf16x8_t*)(Wih + (size_t)(n0 + row) * IN + k0 + kc);
    }
    __syncthreads();
    bf16x8_t a[4], b[4];
    #pragma unroll
    for (int i = 0; i < 4; ++i)
      a[i] = *(const bf16x8_t*)&Alds[(wm + i * 16 + (l & 15)) * AP + ((l >> 4) * 8)];
    #pragma unroll
    for (int i = 0; i < 4; ++i)
      b[i] = *(const bf16x8_t*)&Blds[(wn + i * 16 + (l & 15)) * AP + ((l >> 4) * 8)];
    #pragma unroll
    for (int mi = 0; mi < 4; ++mi) {
      #pragma unroll
      for (int ni = 0; ni < 4; ++ni)
        acc[mi][ni] = __builtin_amdgcn_mfma_f32_16x16x32_bf16(a[mi], b[ni], acc[mi][ni], 0, 0, 0);
    }
    __syncthreads();
  }
  // epilogue: D row = (l>>4)*4 + r, col = l&15  (verified gfx950 C/D layout)
  #pragma unroll
  for (int ni = 0; ni < 4; ++ni) {
    int col = n0 + wn + ni * 16 + (l & 15);
    float bv = bias[col];
    #pragma unroll
    for (int mi = 0; mi < 4; ++mi) {
      int rbase = m0 + wm + mi * 16 + (l >> 4) * 4;
      #pragma unroll
      for (int r = 0; r < 4; ++r)
        xproj[(size_t)(rbase + r) * GDIM + col] = f2bf(acc[mi][ni][r] + bv);
    }
  }
}

// ---------------- per-timestep fused step kernel ----------------
// grid = 256 blocks: blockIdx = bg*64 + hs ; bg in [0,4) batch group of 16,
// hs in [0,64) hidden slice of 16. 4 waves = 4 gates (i,f,g,o).
// Each wave: [16 batch x 16 cols] output tile, K = 1024 (h @ W_hh^T).
template <int FUSED>
__global__ __launch_bounds__(256) void k_step(
    const unsigned short* __restrict__ hprev,
    unsigned short* __restrict__ hnext,
    float* __restrict__ cstate,
    const unsigned short* __restrict__ Whh,
    const unsigned short* __restrict__ Wih,
    const float* __restrict__ x,
    const unsigned short* __restrict__ xproj,
    const float* __restrict__ bias,
    float* __restrict__ out,
    float* __restrict__ hT, float* __restrict__ cT,
    int t, int is_last)
{
  const int RS = 1560;   // padded row stride (shorts): 3120B -> 2-way banks
  const int XB = 1032;   // x-slice column base (fused mode)
  __shared__ unsigned short Hlds[16 * RS];
  __shared__ float Glds[4][16][16];
  const int tid = threadIdx.x;
  const int w = tid >> 6, l = tid & 63;
  const int bg = blockIdx.x >> 6, hs = blockIdx.x & 63;
  const int b0 = bg * 16, n0 = hs * 16;

  // stage h slice: 16 rows x 1024 bf16 (coalesced 16B chunks)
  #pragma unroll
  for (int it = 0; it < 8; ++it) {
    int chunk = tid + it * 256;            // 0..2047
    int row = chunk >> 7;
    int cc  = (chunk & 127) * 8;
    *(bf16x8_t*)&Hlds[row * RS + cc] =
        *(const bf16x8_t*)(hprev + (size_t)(b0 + row) * HID + cc);
  }
  if (FUSED) {
    // stage x[t] slice: 16 rows x 512 fp32 -> bf16
    #pragma unroll
    for (int it = 0; it < 4; ++it) {
      int chunk = tid + it * 256;          // 0..1023
      int row = chunk >> 6;
      int cc  = (chunk & 63) * 8;
      const float* src = x + ((size_t)t * BATCH + b0 + row) * IN + cc;
      float4 f0 = *(const float4*)(src);
      float4 f1 = *(const float4*)(src + 4);
      union { bf16x8_t v; unsigned short s[8]; } u;
      u.s[0]=f2bf(f0.x); u.s[1]=f2bf(f0.y); u.s[2]=f2bf(f0.z); u.s[3]=f2bf(f0.w);
      u.s[4]=f2bf(f1.x); u.s[5]=f2bf(f1.y); u.s[6]=f2bf(f1.z); u.s[7]=f2bf(f1.w);
      *(bf16x8_t*)&Hlds[row * RS + XB + cc] = u.v;
    }
  }
  __syncthreads();

  f32x4_t acc = {0.f, 0.f, 0.f, 0.f};
  const int gcol = (w << 10) + n0 + (l & 15);          // gate column in [0,4096)
  const unsigned short* wp = Whh + (size_t)gcol * HID + ((l >> 4) * 8);
  const unsigned short* ap = &Hlds[(l & 15) * RS + ((l >> 4) * 8)];
  #pragma unroll 4
  for (int ks = 0; ks < 32; ++ks) {
    bf16x8_t a = *(const bf16x8_t*)(ap);
    bf16x8_t b = *(const bf16x8_t*)(wp);
    acc = __builtin_amdgcn_mfma_f32_16x16x32_bf16(a, b, acc, 0, 0, 0);
    ap += 32; wp += 32;
  }
  if (FUSED) {
    const unsigned short* wpx = Wih + (size_t)gcol * IN + ((l >> 4) * 8);
    const unsigned short* apx = &Hlds[(l & 15) * RS + XB + ((l >> 4) * 8)];
    #pragma unroll 4
    for (int ks = 0; ks < 16; ++ks) {
      bf16x8_t a = *(const bf16x8_t*)(apx);
      bf16x8_t b = *(const bf16x8_t*)(wpx);
      acc = __builtin_amdgcn_mfma_f32_16x16x32_bf16(a, b, acc, 0, 0, 0);
      apx += 32; wpx += 32;
    }
  }

  // gate tile -> LDS (D layout: row=(l>>4)*4+r, col=l&15)
  {
    int r0 = (l >> 4) * 4, cc = l & 15;
    Glds[w][r0 + 0][cc] = acc[0];
    Glds[w][r0 + 1][cc] = acc[1];
    Glds[w][r0 + 2][cc] = acc[2];
    Glds[w][r0 + 3][cc] = acc[3];
  }
  __syncthreads();

  // elementwise: one thread per (batch, hidden) element of the tile
  int b = tid >> 4, n = tid & 15;
  float pre[4];
  #pragma unroll
  for (int g = 0; g < 4; ++g) {
    float add;
    if (FUSED) add = bias[(g << 10) + n0 + n];
    else       add = bf2f(xproj[((size_t)t * BATCH + b0 + b) * GDIM + (g << 10) + n0 + n]);
    pre[g] = Glds[g][b][n] + add;
  }
  float ig = sigmoidf_(pre[0]);
  float fg = sigmoidf_(pre[1]);
  float gg = tanhf(pre[2]);
  float og = sigmoidf_(pre[3]);
  size_t ci = (size_t)(b0 + b) * HID + n0 + n;
  float cn = fg * cstate[ci] + ig * gg;
  float hn = og * tanhf(cn);
  cstate[ci] = cn;
  out[((size_t)t * BATCH + b0 + b) * HID + n0 + n] = hn;
  hnext[ci] = f2bf(hn);
  if (is_last) { hT[ci] = hn; cT[ci] = cn; }
}

// ---------------- host launch ----------------
extern "C" void kernel_launch(void* const* d_in, const int* in_sizes, int n_in,
                              void* d_out, int out_size, void* d_ws, size_t ws_size,
                              hipStream_t stream) {
  const float* x    = (const float*)d_in[0];
  const float* Wihf = (const float*)d_in[1];
  const float* bih  = (const float*)d_in[2];
  const float* Whhf = (const float*)d_in[3];
  const float* bhh  = (const float*)d_in[4];
  float* out = (float*)d_out;

  char* ws = (char*)d_ws;
  size_t off = 0;
  auto take = [&](size_t bytes) {
    char* p = ws + off;
    off = (off + bytes + 255) & ~(size_t)255;
    return p;
  };
  unsigned short* wih_b = (unsigned short*)take((size_t)GDIM * IN * 2);    // 4 MB
  unsigned short* whh_b = (unsigned short*)take((size_t)GDIM * HID * 2);   // 8 MB
  float*          bias  = (float*)take((size_t)GDIM * 4);
  unsigned short* h0    = (unsigned short*)take((size_t)BATCH * HID * 2);
  unsigned short* h1    = (unsigned short*)take((size_t)BATCH * HID * 2);
  float*          cbuf  = (float*)take((size_t)BATCH * HID * 4);
  size_t base_need = off;
  unsigned short* xproj = (unsigned short*)take((size_t)MROWS * GDIM * 2); // 256 MB
  size_t full_need = off;
  const int primary = (ws_size >= full_need) ? 1 : 0;
  (void)base_need; (void)in_sizes; (void)n_in; (void)out_size;

  // weight conversions + bias sum + state init
  k_cvt<<<(GDIM * IN / 4 + 255) / 256, 256, 0, stream>>>(Wihf, wih_b, GDIM * IN);
  k_cvt<<<(GDIM * HID / 4 + 255) / 256, 256, 0, stream>>>(Whhf, whh_b, GDIM * HID);
  k_bias<<<(GDIM + 255) / 256, 256, 0, stream>>>(bih, bhh, bias);
  (void)hipMemsetAsync(h0, 0, (size_t)BATCH * HID * 2, stream);
  (void)hipMemsetAsync(cbuf, 0, (size_t)BATCH * HID * 4, stream);

  if (primary) {
    k_xproj<<<dim3(GDIM / 128, MROWS / 128), 256, 0, stream>>>(x, wih_b, bias, xproj);
  }

  float* hT = out + (size_t)T_STEPS * BATCH * HID;
  float* cT = hT + (size_t)BATCH * HID;
  unsigned short* hp = h0;
  unsigned short* hn = h1;
  for (int t = 0; t < T_STEPS; ++t) {
    int last = (t == T_STEPS - 1) ? 1 : 0;
    if (primary)
      k_step<0><<<256, 256, 0, stream>>>(hp, hn, cbuf, whh_b, wih_b, x, xproj, bias,
                                         out, hT, cT, t, last);
    else
      k_step<1><<<256, 256, 0, stream>>>(hp, hn, cbuf, whh_b, wih_b, x, xproj, bias,
                                         out, hT, cT, t, last);
    unsigned short* tmp = hp; hp = hn; hn = tmp;
  }
}